// Round 1
// baseline (606.306 us; speedup 1.0000x reference)
//
#include <hip/hip_runtime.h>
#include <hip/hip_bf16.h>
#include <math.h>

#define S_FRAMES 64
#define C_CH 384
#define HW 3136          // 56*56
#define HW4 784          // HW/4
#define S_TOP 16
#define CNUM 48          // 384/8

// ---------------- Kernel A: global average pool per (s,c) plane ----------------
// grid = 64*384 blocks, 256 threads. Each block reduces one 3136-float plane.
__global__ void pool_kernel(const float* __restrict__ x, float* __restrict__ xg) {
    int bid = blockIdx.x;                       // bid = s*384 + c  (matches x layout)
    const float4* p = (const float4*)(x + (size_t)bid * HW);
    float sum = 0.0f;
    for (int i = threadIdx.x; i < HW4; i += 256) {
        float4 v = p[i];
        sum += (v.x + v.y) + (v.z + v.w);
    }
    // wave-64 shuffle reduce
    for (int off = 32; off > 0; off >>= 1)
        sum += __shfl_down(sum, off, 64);
    __shared__ float red[4];
    int lane = threadIdx.x & 63, wid = threadIdx.x >> 6;
    if (lane == 0) red[wid] = sum;
    __syncthreads();
    if (threadIdx.x == 0) {
        float t = (red[0] + red[1]) + (red[2] + red[3]);
        xg[bid] = t * (1.0f / (float)HW);
    }
}

// ---------------- Kernel B: scores -> top16 -> MLP -> softmax -> convk ----------------
// single block, 256 threads.
__global__ void mlp_kernel(const float* __restrict__ xg,
                           const float* __restrict__ w_lin,
                           const float* __restrict__ w1,
                           const float* __restrict__ bn_g, const float* __restrict__ bn_b,
                           const float* __restrict__ bn_m, const float* __restrict__ bn_v,
                           const float* __restrict__ w2,
                           float* __restrict__ convk) {
    __shared__ float sc[S_FRAMES];
    __shared__ int sel[S_TOP];
    int tid = threadIdx.x;

    // scores: xgs[s] = xg[s,:] . w_lin
    if (tid < S_FRAMES) {
        float s = 0.0f;
        const float* row = xg + (size_t)tid * C_CH;
        for (int c = 0; c < C_CH; c++) s += row[c] * w_lin[c];
        sc[tid] = s;
    }
    __syncthreads();

    // stable top-16 (descending score, tie -> lower index), kept in temporal order.
    // threads 0..63 are exactly wave 0 -> 64-bit ballot is the selection mask.
    if (tid < S_FRAMES) {
        float my = sc[tid];
        int rank = 0;
        for (int s2 = 0; s2 < S_FRAMES; s2++) {
            float o = sc[s2];
            rank += (o > my) || (o == my && s2 < tid);
        }
        bool selected = (rank < S_TOP);
        unsigned long long mask = __ballot(selected);
        if (selected) {
            int pos = __popcll(mask & ((1ull << tid) - 1ull)); // ascending-index position
            sel[pos] = tid;
        }
    }
    __syncthreads();

    // per-channel MLP: (16) -> (32) -> BN -> ReLU -> (3) -> softmax
    for (int c = tid; c < C_CH; c += 256) {
        float sls[S_TOP];
        for (int j = 0; j < S_TOP; j++) sls[j] = xg[(size_t)sel[j] * C_CH + c];
        float lg0 = 0.f, lg1 = 0.f, lg2 = 0.f;
        for (int o = 0; o < 2 * S_TOP; o++) {
            float h = 0.0f;
            const float* w1row = w1 + o * S_TOP;
            for (int j = 0; j < S_TOP; j++) h += sls[j] * w1row[j];
            h = (h - bn_m[o]) * (bn_g[o] / sqrtf(bn_v[o] + 1e-5f)) + bn_b[o];
            h = fmaxf(h, 0.0f);
            lg0 += h * w2[0 * 2 * S_TOP + o];
            lg1 += h * w2[1 * 2 * S_TOP + o];
            lg2 += h * w2[2 * 2 * S_TOP + o];
        }
        float mx = fmaxf(lg0, fmaxf(lg1, lg2));
        float e0 = expf(lg0 - mx), e1 = expf(lg1 - mx), e2 = expf(lg2 - mx);
        float inv = 1.0f / (e0 + e1 + e2);
        convk[c * 3 + 0] = e0 * inv;
        convk[c * 3 + 1] = e1 * inv;
        convk[c * 3 + 2] = e2 * inv;
    }
}

// ---------------- Kernel C: temporal shift + 3-tap depthwise temporal conv ----------------
// One thread per (c, hw float4 column); streams s with a sliding 3-tap window so x
// is read exactly once. Shift folded into tap index:
//   c <  48 : value(u) = x[u+1], valid u in [0,62]
//   c <  96 : value(u) = x[u-1], valid u in [1,63]
//   else    : value(u) = x[u],   valid u in [0,63]
// out[s] = k0*V(s-1) + k1*V(s) + k2*V(s+1)
__global__ void conv_kernel(const float* __restrict__ x,
                            const float* __restrict__ convk,
                            float* __restrict__ out) {
    int idx = blockIdx.x * blockDim.x + threadIdx.x;
    if (idx >= C_CH * HW4) return;
    int c   = idx / HW4;
    int col = idx - c * HW4;

    float k0 = convk[c * 3 + 0];
    float k1 = convk[c * 3 + 1];
    float k2 = convk[c * 3 + 2];

    int delta, lo, hi;
    if (c < CNUM)          { delta =  1; lo = 0; hi = 62; }
    else if (c < 2 * CNUM) { delta = -1; lo = 1; hi = 63; }
    else                   { delta =  0; lo = 0; hi = 63; }

    const size_t S = (size_t)C_CH * HW4;       // float4 stride per frame
    const float4* xp = (const float4*)x + (size_t)c * HW4 + col;
    float4*       op = (float4*)out    + (size_t)c * HW4 + col;

    const float4 zero = make_float4(0.f, 0.f, 0.f, 0.f);
    float4 vm = zero;
    float4 vc = (0 >= lo) ? xp[(size_t)delta * S] : zero;   // V(0); hi>=0 always

    for (int s = 0; s < S_FRAMES; s++) {
        int u = s + 1;
        float4 vp = (u >= lo && u <= hi) ? xp[(size_t)(u + delta) * S] : zero;
        float4 o;
        o.x = k0 * vm.x + k1 * vc.x + k2 * vp.x;
        o.y = k0 * vm.y + k1 * vc.y + k2 * vp.y;
        o.z = k0 * vm.z + k1 * vc.z + k2 * vp.z;
        o.w = k0 * vm.w + k1 * vc.w + k2 * vp.w;
        op[(size_t)s * S] = o;
        vm = vc; vc = vp;
    }
}

extern "C" void kernel_launch(void* const* d_in, const int* in_sizes, int n_in,
                              void* d_out, int out_size, void* d_ws, size_t ws_size,
                              hipStream_t stream) {
    const float* x       = (const float*)d_in[0];
    const float* w_lin   = (const float*)d_in[1];
    const float* w1      = (const float*)d_in[2];
    const float* bn_g    = (const float*)d_in[3];
    const float* bn_b    = (const float*)d_in[4];
    const float* bn_m    = (const float*)d_in[5];
    const float* bn_v    = (const float*)d_in[6];
    const float* w2      = (const float*)d_in[7];
    float* out = (float*)d_out;

    float* xg    = (float*)d_ws;               // 64*384 floats
    float* convk = xg + S_FRAMES * C_CH;       // 384*3 floats

    pool_kernel<<<S_FRAMES * C_CH, 256, 0, stream>>>(x, xg);
    mlp_kernel<<<1, 256, 0, stream>>>(xg, w_lin, w1, bn_g, bn_b, bn_m, bn_v, w2, convk);
    conv_kernel<<<(C_CH * HW4 + 255) / 256, 256, 0, stream>>>(x, convk, out);
}